// Round 17
// baseline (169.454 us; speedup 1.0000x reference)
//
#include <hip/hip_runtime.h>
#include <hip/hip_bf16.h>
#include <cstdint>

// MultiHeadSelfAttention: B=4 S=4096 E=768 H=8 D=96. Inputs/outputs f32.
// Pipeline: conv_w + conv3 (f32->bf16; Xk/Xv scratch in d_out) ->
// batched QKV GEMM (128x128 tile, FOUR-buffer LDS, stage-3-ahead,
// counted vmcnt(8) retiring 2-step-old loads, setprio MFMA) -> per-token
// 8x8 head-gram attention -> final GEMM (256x128, 3-buffer r13) + bias.

typedef unsigned short u16;
typedef short bf16x8 __attribute__((ext_vector_type(8)));
typedef float f32x4 __attribute__((ext_vector_type(4)));

#define B_  4
#define S_  4096
#define E_  768
#define H_  8
#define D_  96
#define T_  (B_*S_)            // 16384 tokens

static __device__ __forceinline__ u16 f2bf(float f) {
  unsigned u = __builtin_bit_cast(unsigned, f);
  u += 0x7fffu + ((u >> 16) & 1u);           // round-to-nearest-even
  return (u16)(u >> 16);
}
static __device__ __forceinline__ unsigned pk2(float lo, float hi) {
  return (unsigned)f2bf(lo) | ((unsigned)f2bf(hi) << 16);
}
static __device__ __forceinline__ float bflo(unsigned u) {
  return __builtin_bit_cast(float, u << 16);
}
static __device__ __forceinline__ float bfhi(unsigned u) {
  return __builtin_bit_cast(float, u & 0xffff0000u);
}

// ---------------- f32 -> bf16 convert, all 4 weight matrices (E*E each)
__global__ __launch_bounds__(256) void conv_w(
    const float* __restrict__ w0, const float* __restrict__ w1,
    const float* __restrict__ w2, const float* __restrict__ w3,
    u16* __restrict__ dst)
{
  const int bpw = (E_ * E_ / 4) / 256;            // 576 blocks per weight
  const int which = blockIdx.x / bpw;
  const float* src = which == 0 ? w0 : which == 1 ? w1 : which == 2 ? w2 : w3;
  const int i = (blockIdx.x - which * bpw) * 256 + threadIdx.x;
  const float4 v = ((const float4*)src)[i];
  uint2 w;
  w.x = pk2(v.x, v.y);
  w.y = pk2(v.z, v.w);
  ((uint2*)(dst + (size_t)which * E_ * E_))[i] = w;
}

// ---------------- f32 -> bf16 convert, q/k/v activations in one launch
__global__ __launch_bounds__(256) void conv3(
    const float* __restrict__ q, const float* __restrict__ k,
    const float* __restrict__ v, u16* __restrict__ xq,
    u16* __restrict__ xk, u16* __restrict__ xv)
{
  const int w = blockIdx.y;
  const float* src = w == 0 ? q : w == 1 ? k : v;
  u16* dst = w == 0 ? xq : w == 1 ? xk : xv;
  const int i = blockIdx.x * 256 + threadIdx.x;   // float4 index
  const float4 vv = ((const float4*)src)[i];
  uint2 o;
  o.x = pk2(vv.x, vv.y);
  o.y = pk2(vv.z, vv.w);
  ((uint2*)dst)[i] = o;
}

#define GLOAD(SRC, DST)                                                        \
  __builtin_amdgcn_global_load_lds(                                            \
      (const __attribute__((address_space(1))) void*)(SRC),                    \
      (__attribute__((address_space(3))) void*)(DST), 16, 0, 0)

// ============ batched QKV GEMM: C = A x W^T, bf16 out ============
// 128x128 tile, 4 waves (2x2, 64x64/wave), 24 K-steps of 32.
// FOUR-buffer LDS (4 x 16KB = 64KB -> 2 blocks/CU): step t reads buf[t%4],
// stages tile t+3 into buf[(t+3)%4] (3-step cover), step-end wait
// vmcnt(8) retires 2-STEP-OLD loads (~1100cyc, covers HBM latency) so the
// barrier is pure rendezvous. Tail: vm 8,8,4,0. Swizzle: slot g^((r>>1)&3).

#define QSTAGE(BUF, KT)                                                        \
  {                                                                            \
    _Pragma("unroll")                                                          \
    for (int c = 0; c < 2; ++c) {                                              \
      const int idx = (c << 8) + tid;                                          \
      const int r = idx >> 2, g = idx & 3;                                     \
      const int gs = g ^ ((r >> 1) & 3);                                       \
      GLOAD(A + (size_t)(tM + r) * E_ + (KT) + (gs << 3),                      \
            &lds[BUF][0][((c << 8) + (wave << 6)) << 3]);                      \
      GLOAD(Wt + (size_t)(tN + r) * E_ + (KT) + (gs << 3),                     \
            &lds[BUF][1][((c << 8) + (wave << 6)) << 3]);                      \
    }                                                                          \
  }

#define QLOADFRAGS(BUF)                                                        \
  {                                                                            \
    _Pragma("unroll")                                                          \
    for (int m = 0; m < 4; ++m)                                                \
      a[m] = *(const bf16x8*)&lds[BUF][0][(((wr << 6) + (m << 4) + l15) << 5) + slotOff]; \
    _Pragma("unroll")                                                          \
    for (int n = 0; n < 4; ++n)                                                \
      b[n] = *(const bf16x8*)&lds[BUF][1][(((wc << 6) + (n << 4) + l15) << 5) + slotOff]; \
  }

#define QDOMFMA()                                                              \
  {                                                                            \
    __builtin_amdgcn_s_setprio(1);                                             \
    _Pragma("unroll")                                                          \
    for (int m = 0; m < 4; ++m)                                                \
      _Pragma("unroll")                                                        \
      for (int n = 0; n < 4; ++n)                                              \
        acc[m][n] = __builtin_amdgcn_mfma_f32_16x16x32_bf16(a[m], b[n], acc[m][n], 0, 0, 0); \
    __builtin_amdgcn_s_setprio(0);                                             \
  }

#define QSTEP(RB, SB, KT, STG, VM)                                             \
  {                                                                            \
    bf16x8 a[4], b[4];                                                         \
    QLOADFRAGS(RB);                                                            \
    if (STG) QSTAGE(SB, KT);                                                   \
    QDOMFMA();                                                                 \
    asm volatile("s_waitcnt vmcnt(" #VM ")\n\ts_barrier" ::: "memory");        \
  }

__global__ __launch_bounds__(256, 2) void gemm_q(
    const u16* __restrict__ a0, const u16* __restrict__ a1,
    const u16* __restrict__ a2, const u16* __restrict__ Wall,
    u16* __restrict__ c0, u16* __restrict__ c1, u16* __restrict__ c2)
{
  __shared__ u16 lds[4][2][4096];                // [buf][A/B][128x32] = 64KB
  const int q_ = blockIdx.y;
  const u16* A  = q_ == 0 ? a0 : q_ == 1 ? a1 : a2;
  const u16* Wt = Wall + (size_t)q_ * (E_ * E_);
  u16* Cv = q_ == 0 ? c0 : q_ == 1 ? c1 : c2;

  // anti-convoy stagger
  {
    int sidx = ((blockIdx.x >> 8) + q_) % 3;
#pragma unroll 1
    for (int z = 0; z < sidx; ++z) __builtin_amdgcn_s_sleep(3);
  }

  const int tid  = threadIdx.x;
  const int wave = tid >> 6;
  const int lane = tid & 63;
  const int wr = wave >> 1, wc = wave & 1;       // 2x2 wave grid, 64x64/wave
  // XCD-chunked swizzle: 768 x-blocks, 96/XCD -> 16 M-panels x 6 N per XCD
  const int bid = blockIdx.x;
  const int wg  = (bid & 7) * 96 + (bid >> 3);
  const int mT  = wg / 6;
  const int nT  = wg - mT * 6;
  const int tM = mT << 7, tN = nT << 7;
  const int l15 = lane & 15, l4 = lane >> 4;
  const int slotOff = (l4 ^ ((l15 >> 1) & 3)) << 3;

  f32x4 acc[4][4] = {};

  // prologue: stage tiles 0,1,2 (12 loads); retire tile0's 4; barrier
  QSTAGE(0, 0);
  QSTAGE(1, 32);
  QSTAGE(2, 64);
  asm volatile("s_waitcnt vmcnt(8)\n\ts_barrier" ::: "memory");

  // steady state: t = 0..19 (5 groups of 4); step t stages tile t+3
#pragma unroll 1
  for (int it = 0; it < 5; ++it) {
    const int kb = it << 7;                      // t*32 base for the group
    QSTEP(0, 3, kb + 96,  true, 8);
    QSTEP(1, 0, kb + 128, true, 8);
    QSTEP(2, 1, kb + 160, true, 8);
    QSTEP(3, 2, kb + 192, true, 8);
  }
  // tail: t=20 stages tile23; t=21..23 drain progressively
  QSTEP(0, 3, 736, true, 8);
  QSTEP(1, 0, 0, false, 4);
  QSTEP(2, 0, 0, false, 0);
  {
    bf16x8 a[4], b[4];
    QLOADFRAGS(3);
    QDOMFMA();
  }

  // epilogue: C/D layout col=lane&15, row=(lane>>4)*4+reg  [m89/m91]
  // stage C tile (128x128 u16 = 32KB) in LDS, write back coalesced
  __syncthreads();
  u16* lC = (u16*)lds;
#pragma unroll
  for (int m = 0; m < 4; ++m)
#pragma unroll
    for (int n = 0; n < 4; ++n) {
      const int row = (wr << 6) + (m << 4) + (l4 << 2);
      const int col = (wc << 6) + (n << 4) + l15;
#pragma unroll
      for (int r = 0; r < 4; ++r)
        lC[(row + r) * 128 + col] = f2bf(acc[m][n][r]);
    }
  __syncthreads();
#pragma unroll
  for (int p = 0; p < 8; ++p) {
    const int row = (p << 4) + (wave << 2) + l4;   // 16 rows per pass
    const bf16x8 v = *(const bf16x8*)&lC[row * 128 + (l15 << 3)];
    *(bf16x8*)(Cv + (size_t)(tM + row) * E_ + tN + (l15 << 3)) = v;
  }
}

// ============ final GEMM: C = A x W^T + bias, f32 out (r13 structure) ====
// 256x128 tile, 4 waves (2x2, wave-tile 128x64), 24 K-steps of 32,
// TRIPLE-buffered LDS (3 x 24KB = 72KB), counted vmcnt(6), setprio.

#define FSTAGE(BUF, KT)                                                        \
  {                                                                            \
    _Pragma("unroll")                                                          \
    for (int c = 0; c < 4; ++c) {                                              \
      const int idx = (c << 8) + tid;                                          \
      const int r = idx >> 2, g = idx & 3;                                     \
      const int gs = g ^ ((r >> 1) & 3);                                       \
      GLOAD(A + (size_t)(tM + r) * E_ + (KT) + (gs << 3),                      \
            &lds[(BUF) * 12288 + (((c << 8) + (wave << 6)) << 3)]);            \
    }                                                                          \
    _Pragma("unroll")                                                          \
    for (int c = 0; c < 2; ++c) {                                              \
      const int idx = (c << 8) + tid;                                          \
      const int r = idx >> 2, g = idx & 3;                                     \
      const int gs = g ^ ((r >> 1) & 3);                                       \
      GLOAD(Wt + (size_t)(tN + r) * E_ + (KT) + (gs << 3),                     \
            &lds[(BUF) * 12288 + 8192 + (((c << 8) + (wave << 6)) << 3)]);     \
    }                                                                          \
  }

#define FLOADFRAGS(BUF)                                                        \
  {                                                                            \
    _Pragma("unroll")                                                          \
    for (int m = 0; m < 8; ++m)                                                \
      a[m] = *(const bf16x8*)&lds[(BUF) * 12288 +                              \
                 (((wr << 7) + (m << 4) + l15) << 5) + slotOff];               \
    _Pragma("unroll")                                                          \
    for (int n = 0; n < 4; ++n)                                                \
      b[n] = *(const bf16x8*)&lds[(BUF) * 12288 + 8192 +                       \
                 (((wc << 6) + (n << 4) + l15) << 5) + slotOff];               \
  }

#define FDOMFMA()                                                              \
  {                                                                            \
    __builtin_amdgcn_s_setprio(1);                                             \
    _Pragma("unroll")                                                          \
    for (int m = 0; m < 8; ++m)                                                \
      _Pragma("unroll")                                                        \
      for (int n = 0; n < 4; ++n)                                              \
        acc[m][n] = __builtin_amdgcn_mfma_f32_16x16x32_bf16(a[m], b[n], acc[m][n], 0, 0, 0); \
    __builtin_amdgcn_s_setprio(0);                                             \
  }

#define FSTEP(RB, SB, KT, STG, VM)                                             \
  {                                                                            \
    bf16x8 a[8], b[4];                                                         \
    FLOADFRAGS(RB);                                                            \
    if (STG) FSTAGE(SB, KT);                                                   \
    FDOMFMA();                                                                 \
    asm volatile("s_waitcnt vmcnt(" #VM ")\n\ts_barrier" ::: "memory");        \
  }

__global__ __launch_bounds__(256, 2) void gemm_f(
    const u16* __restrict__ A, const u16* __restrict__ Wt,
    const float* __restrict__ bias, float* __restrict__ Cv)
{
  __shared__ u16 lds[3 * 12288];                 // 72 KB

  // anti-convoy stagger
  {
    const int sidx = blockIdx.x >> 7;            // 0..2 within a 384-grid
#pragma unroll 1
    for (int z = 0; z < sidx; ++z) __builtin_amdgcn_s_sleep(3);
  }

  const int tid  = threadIdx.x;
  const int wave = tid >> 6;
  const int lane = tid & 63;
  const int wr = wave >> 1, wc = wave & 1;       // 2x2 grid, 128x64/wave
  // XCD-chunked swizzle: 384 x-blocks, 48/XCD -> 8 M-panels x 6 N per XCD
  const int bid = blockIdx.x;
  const int wg  = (bid & 7) * 48 + (bid >> 3);
  const int mT  = wg / 6;
  const int nT  = wg - mT * 6;
  const int tM = mT << 8, tN = nT << 7;
  const int l15 = lane & 15, l4 = lane >> 4;
  const int slotOff = (l4 ^ ((l15 >> 1) & 3)) << 3;

  f32x4 acc[8][4] = {};

  FSTAGE(0, 0);
  FSTAGE(1, 32);
  asm volatile("s_waitcnt vmcnt(6)\n\ts_barrier" ::: "memory");

#pragma unroll 1
  for (int it = 0; it < 7; ++it) {
    const int kt = it * 96;
    FSTEP(0, 2, kt + 64,  true, 6);
    FSTEP(1, 0, kt + 96,  true, 6);
    FSTEP(2, 1, kt + 128, true, 6);
  }
  FSTEP(0, 2, 736, true, 6);
  FSTEP(1, 0, 0,   false, 0);
  {
    bf16x8 a[8], b[4];
    FLOADFRAGS(2);
    FDOMFMA();
  }

  // epilogue: f32 direct stores (full 64B lines), +bias
#pragma unroll
  for (int m = 0; m < 8; ++m) {
#pragma unroll
    for (int n = 0; n < 4; ++n) {
      const int row = tM + (wr << 7) + (m << 4) + (l4 << 2);
      const int col = tN + (wc << 6) + (n << 4) + l15;
      const float badd = bias[col];
#pragma unroll
      for (int r = 0; r < 4; ++r)
        Cv[(size_t)(row + r) * E_ + col] = acc[m][n][r] + badd;
    }
  }
}

// ---------------- per-token attention: 1 wave per token
// att[i,j] = sum_d Q[t,i*96+d]*K[t,j*96+d]; masked softmax over j;
// out2D[b, 512*i + s/8, 96*(s%8)+d] = sum_j p[i,j]*V[t, j*96+d]
__global__ __launch_bounds__(256) void attn_tok(
    const u16* __restrict__ Q, const u16* __restrict__ K,
    const u16* __restrict__ V, const int* __restrict__ mask,
    u16* __restrict__ O)
{
  __shared__ float pl[4][8][8];
  const int tid = threadIdx.x, wave = tid >> 6, lane = tid & 63;
  const int t = blockIdx.x * 4 + wave;
  const int s = t & (S_ - 1);
  const int b = t >> 12;
  const int i = lane >> 3, j = lane & 7;

  const uint4* qp = (const uint4*)(Q + (size_t)t * E_ + i * D_);
  const uint4* kp = (const uint4*)(K + (size_t)t * E_ + j * D_);
  float acc = 0.f;
#pragma unroll
  for (int it = 0; it < 12; ++it) {   // 96 bf16 = 12 x uint4
    const uint4 qv = qp[it], kv = kp[it];
    acc += bflo(qv.x) * bflo(kv.x) + bfhi(qv.x) * bfhi(kv.x);
    acc += bflo(qv.y) * bflo(kv.y) + bfhi(qv.y) * bfhi(kv.y);
    acc += bflo(qv.z) * bflo(kv.z) + bfhi(qv.z) * bfhi(kv.z);
    acc += bflo(qv.w) * bflo(kv.w) + bfhi(qv.w) * bfhi(kv.w);
  }
  // mask==0 -> -1e20 everywhere -> softmax degenerates to 1/8
  float sv = (mask[t] == 0) ? -1e20f : acc;
  sv *= 0.03608439182435161f;          // 1/sqrt(768)
  float mx = sv;
  mx = fmaxf(mx, __shfl_xor(mx, 1));
  mx = fmaxf(mx, __shfl_xor(mx, 2));
  mx = fmaxf(mx, __shfl_xor(mx, 4));
  const float e = __expf(sv - mx);
  float sm = e;
  sm += __shfl_xor(sm, 1);
  sm += __shfl_xor(sm, 2);
  sm += __shfl_xor(sm, 4);
  pl[wave][i][j] = e / sm;
  __syncthreads();

  // PV: lane (i2, db) owns d = db*12 .. db*12+11 of head i2
  const int i2 = lane >> 3, db = lane & 7;
  float o[12] = {};
#pragma unroll
  for (int jj = 0; jj < 8; ++jj) {
    const float pj = pl[wave][i2][jj];
    const uint2* vp = (const uint2*)(V + (size_t)t * E_ + jj * D_ + db * 12);
    const uint2 v0 = vp[0], v1 = vp[1], v2 = vp[2];
    o[0]  += pj * bflo(v0.x);  o[1]  += pj * bfhi(v0.x);
    o[2]  += pj * bflo(v0.y);  o[3]  += pj * bfhi(v0.y);
    o[4]  += pj * bflo(v1.x);  o[5]  += pj * bfhi(v1.x);
    o[6]  += pj * bflo(v1.y);  o[7]  += pj * bfhi(v1.y);
    o[8]  += pj * bflo(v2.x);  o[9]  += pj * bfhi(v2.x);
    o[10] += pj * bflo(v2.y);  o[11] += pj * bfhi(v2.y);
  }
  // scrambled reshape [b,h,s,d] -> [b, 512h + s/8, 96(s%8)+d]
  const size_t row = (size_t)b * S_ + 512 * i2 + (s >> 3);
  u16* op = O + row * E_ + 96 * (s & 7) + db * 12;
  uint2 w0, w1, w2;
  w0.x = pk2(o[0], o[1]);
  w0.y = pk2(o[2], o[3]);
  w1.x = pk2(o[4], o[5]);
  w1.y = pk2(o[6], o[7]);
  w2.x = pk2(o[8], o[9]);
  w2.y = pk2(o[10], o[11]);
  ((uint2*)op)[0] = w0;
  ((uint2*)op)[1] = w1;
  ((uint2*)op)[2] = w2;
}

extern "C" void kernel_launch(void* const* d_in, const int* in_sizes, int n_in,
                              void* d_out, int out_size, void* d_ws, size_t ws_size,
                              hipStream_t stream)
{
  const float* values = (const float*)d_in[0];
  const float* keys   = (const float*)d_in[1];
  const float* query  = (const float*)d_in[2];
  const int*   mask   = (const int*)d_in[3];
  const float* Wv = (const float*)d_in[4];
  const float* Wk = (const float*)d_in[5];
  const float* Wq = (const float*)d_in[6];
  const float* Wo = (const float*)d_in[7];
  const float* bo = (const float*)d_in[8];

  const size_t TE = (size_t)T_ * E_;
  const size_t EE = (size_t)E_ * E_;
  u16* Qb = (u16*)d_ws;          // 25.2 MB each (bf16)
  u16* Kb = Qb + TE;
  u16* Vb = Kb + TE;
  u16* Xq = Vb + TE;             // Xq scratch; later aliased as O2
  u16* Wb = Xq + TE;             // 4 x 1.18 MB bf16 weights (110.1 MB total)
  // Xk/Xv live in d_out (50.33 MB = exactly 2 x TE bf16); dead before the
  // final GEMM overwrites d_out.
  u16* Xk = (u16*)d_out;
  u16* Xv = Xk + TE;

  dim3 blk(256);

  // weights: Wq,Wk,Wv,Wo -> Wb
  conv_w<<<dim3(4 * (E_ * E_ / 4) / 256), blk, 0, stream>>>(Wq, Wk, Wv, Wo, Wb);

  // activations: query->Xq, keys->Xk, values->Xv (one launch)
  conv3<<<dim3(TE / 4 / 256, 3), blk, 0, stream>>>(query, keys, values, Xq, Xk, Xv);

  // batched QKV GEMM: y=0: Xq*Wq->Qb, y=1: Xk*Wk->Kb, y=2: Xv*Wv->Vb
  gemm_q<<<dim3(T_ / 128 * 6, 3), blk, 0, stream>>>(
      Xq, Xk, Xv, Wb, Qb, Kb, Vb);

  // attention -> O2 (reuses Xq slot; Xq dead after the batched GEMM)
  attn_tok<<<dim3(T_ / 4), blk, 0, stream>>>(Qb, Kb, Vb, mask, Xq /*O2*/);

  // final GEMM: O2 * Wo^T + bo -> d_out (f32); overwrites Xk/Xv scratch
  gemm_f<<<dim3(T_ / 256 * 6), blk, 0, stream>>>(
      Xq /*O2*/, Wb + 3 * EE, bo, (float*)d_out);
}

// Round 18
// 164.697 us; speedup vs baseline: 1.0289x; 1.0289x over previous
//
#include <hip/hip_runtime.h>
#include <hip/hip_bf16.h>
#include <cstdint>

// MultiHeadSelfAttention: B=4 S=4096 E=768 H=8 D=96. Inputs/outputs f32.
// BEST-KNOWN CONFIG (r13, 165.6us) restored verbatim:
// weight conv -> batched conv (q,k,v; Xk/Xv scratch in d_out) ->
// ONE batched QKV GEMM (256x128 tile, wave-tile 128x64, TRIPLE-buffered LDS,
// counted vmcnt(6) + raw s_barrier, setprio MFMA) -> per-token 8x8 head-gram
// attention -> scrambled reshape -> final GEMM + bias.

typedef unsigned short u16;
typedef short bf16x8 __attribute__((ext_vector_type(8)));
typedef float f32x4 __attribute__((ext_vector_type(4)));

#define B_  4
#define S_  4096
#define E_  768
#define H_  8
#define D_  96
#define T_  (B_*S_)            // 16384 tokens
#define BM_ 256
#define BN_ 128
#define NT_ (E_/BN_)           // 6 N-tiles

static __device__ __forceinline__ u16 f2bf(float f) {
  unsigned u = __builtin_bit_cast(unsigned, f);
  u += 0x7fffu + ((u >> 16) & 1u);           // round-to-nearest-even
  return (u16)(u >> 16);
}
static __device__ __forceinline__ unsigned pk2(float lo, float hi) {
  return (unsigned)f2bf(lo) | ((unsigned)f2bf(hi) << 16);
}
static __device__ __forceinline__ float bflo(unsigned u) {
  return __builtin_bit_cast(float, u << 16);
}
static __device__ __forceinline__ float bfhi(unsigned u) {
  return __builtin_bit_cast(float, u & 0xffff0000u);
}

// ---------------- f32 -> bf16 convert, all 4 weight matrices (E*E each)
__global__ __launch_bounds__(256) void conv_w(
    const float* __restrict__ w0, const float* __restrict__ w1,
    const float* __restrict__ w2, const float* __restrict__ w3,
    u16* __restrict__ dst)
{
  const int bpw = (E_ * E_ / 4) / 256;            // 576 blocks per weight
  const int which = blockIdx.x / bpw;
  const float* src = which == 0 ? w0 : which == 1 ? w1 : which == 2 ? w2 : w3;
  const int i = (blockIdx.x - which * bpw) * 256 + threadIdx.x;
  const float4 v = ((const float4*)src)[i];
  uint2 w;
  w.x = pk2(v.x, v.y);
  w.y = pk2(v.z, v.w);
  ((uint2*)(dst + (size_t)which * E_ * E_))[i] = w;
}

// ---------------- f32 -> bf16 convert, q/k/v activations in one launch
__global__ __launch_bounds__(256) void conv3(
    const float* __restrict__ q, const float* __restrict__ k,
    const float* __restrict__ v, u16* __restrict__ xq,
    u16* __restrict__ xk, u16* __restrict__ xv)
{
  const int w = blockIdx.y;
  const float* src = w == 0 ? q : w == 1 ? k : v;
  u16* dst = w == 0 ? xq : w == 1 ? xk : xv;
  const int i = blockIdx.x * 256 + threadIdx.x;   // float4 index
  const float4 vv = ((const float4*)src)[i];
  uint2 o;
  o.x = pk2(vv.x, vv.y);
  o.y = pk2(vv.z, vv.w);
  ((uint2*)dst)[i] = o;
}

// ---------------- GEMM: C[T_,E_] = A[T_,E_](bf16) x W[E_,E_](bf16)^T (+bias)
// 256x128 tile, 256 thr (4 waves 2x2, WAVE-TILE 128x64), 24 K-steps of 32.
// TRIPLE-buffered LDS (3 x 24KB = 72KB -> 2 blocks/CU): step t reads
// buf[t%3], stages buf[(t+2)%3] (2 steps of cover), then
// s_waitcnt vmcnt(6) (retire step t-1's 6 loads, keep step t's 6 flying)
// + raw s_barrier. setprio(1) around the 32-MFMA cluster (T5).
// Granule swizzle: slot g ^ ((r>>1)&3). BATCHED: blockIdx.y selects Q/K/V.

#define GLOAD(SRC, DST)                                                        \
  __builtin_amdgcn_global_load_lds(                                            \
      (const __attribute__((address_space(1))) void*)(SRC),                    \
      (__attribute__((address_space(3))) void*)(DST), 16, 0, 0)

// buf i: A at u16-idx i*12288 (256x32 = 16KB), B at i*12288+8192 (128x32)
#define STAGE(BUF, KT)                                                         \
  {                                                                            \
    _Pragma("unroll")                                                          \
    for (int c = 0; c < 4; ++c) {                                              \
      const int idx = (c << 8) + tid;                                          \
      const int r = idx >> 2, g = idx & 3;                                     \
      const int gs = g ^ ((r >> 1) & 3);                                       \
      GLOAD(A + (size_t)(tM + r) * E_ + (KT) + (gs << 3),                      \
            &lds[(BUF) * 12288 + (((c << 8) + (wave << 6)) << 3)]);            \
    }                                                                          \
    _Pragma("unroll")                                                          \
    for (int c = 0; c < 2; ++c) {                                              \
      const int idx = (c << 8) + tid;                                          \
      const int r = idx >> 2, g = idx & 3;                                     \
      const int gs = g ^ ((r >> 1) & 3);                                       \
      GLOAD(Wt + (size_t)(tN + r) * E_ + (KT) + (gs << 3),                     \
            &lds[(BUF) * 12288 + 8192 + (((c << 8) + (wave << 6)) << 3)]);     \
    }                                                                          \
  }

#define LOADFRAGS(BUF)                                                         \
  {                                                                            \
    _Pragma("unroll")                                                          \
    for (int m = 0; m < 8; ++m)                                                \
      a[m] = *(const bf16x8*)&lds[(BUF) * 12288 +                              \
                 (((wr << 7) + (m << 4) + l15) << 5) + slotOff];               \
    _Pragma("unroll")                                                          \
    for (int n = 0; n < 4; ++n)                                                \
      b[n] = *(const bf16x8*)&lds[(BUF) * 12288 + 8192 +                       \
                 (((wc << 6) + (n << 4) + l15) << 5) + slotOff];               \
  }

#define DOMFMA()                                                               \
  {                                                                            \
    __builtin_amdgcn_s_setprio(1);                                             \
    _Pragma("unroll")                                                          \
    for (int m = 0; m < 8; ++m)                                                \
      _Pragma("unroll")                                                        \
      for (int n = 0; n < 4; ++n)                                              \
        acc[m][n] = __builtin_amdgcn_mfma_f32_16x16x32_bf16(a[m], b[n], acc[m][n], 0, 0, 0); \
    __builtin_amdgcn_s_setprio(0);                                             \
  }

#define STEP(RB, SB, KT, STG, VM)                                              \
  {                                                                            \
    bf16x8 a[8], b[4];                                                         \
    LOADFRAGS(RB);                                                             \
    if (STG) STAGE(SB, KT);                                                    \
    DOMFMA();                                                                  \
    asm volatile("s_waitcnt vmcnt(" #VM ")\n\ts_barrier" ::: "memory");        \
  }

template<bool BATCHED, bool OUT_F32, bool BIAS>
__global__ __launch_bounds__(256, 2) void gemm_nt(
    const u16* __restrict__ a0, const u16* __restrict__ a1,
    const u16* __restrict__ a2, const u16* __restrict__ Wall,
    const float* __restrict__ bias,
    void* __restrict__ c0, void* __restrict__ c1, void* __restrict__ c2)
{
  __shared__ u16 lds[3 * 12288];                 // 72 KB
  const u16* A;
  const u16* Wt;
  void* Cv;
  if constexpr (BATCHED) {
    const int q_ = blockIdx.y;
    A  = q_ == 0 ? a0 : q_ == 1 ? a1 : a2;
    Wt = Wall + (size_t)q_ * (E_ * E_);
    Cv = q_ == 0 ? c0 : q_ == 1 ? c1 : c2;
  } else {
    A = a0; Wt = Wall; Cv = c0;
  }

  // anti-convoy stagger: offset co-resident cohorts
  {
    int sidx = blockIdx.x >> 7;                  // 0..2 within a 384-grid
    if constexpr (BATCHED) sidx = (sidx + blockIdx.y) % 3;
#pragma unroll 1
    for (int z = 0; z < sidx; ++z) __builtin_amdgcn_s_sleep(3);
  }

  const int tid  = threadIdx.x;
  const int wave = tid >> 6;
  const int lane = tid & 63;
  const int wr = wave >> 1, wc = wave & 1;       // 2x2 grid, 128x64/wave
  // XCD-chunked swizzle: 384 x-blocks, 48/XCD -> 8 M-panels x 6 N per XCD
  const int bid = blockIdx.x;
  const int wg  = (bid & 7) * 48 + (bid >> 3);
  const int mT  = wg / NT_;
  const int nT  = wg - mT * NT_;
  const int tM = mT * BM_, tN = nT * BN_;
  const int l15 = lane & 15, l4 = lane >> 4;
  const int slotOff = (l4 ^ ((l15 >> 1) & 3)) << 3;

  f32x4 acc[8][4] = {};

  // prologue: stage steps 0,1 (12 loads); retire step 0's 6; barrier
  STAGE(0, 0);
  STAGE(1, 32);
  asm volatile("s_waitcnt vmcnt(6)\n\ts_barrier" ::: "memory");

  // steady state: t = 0..20 (7 groups of 3, static buf indices)
#pragma unroll 1
  for (int it = 0; it < 7; ++it) {
    const int kt = it * 96;
    STEP(0, 2, kt + 64,  true, 6);
    STEP(1, 0, kt + 96,  true, 6);
    STEP(2, 1, kt + 128, true, 6);
  }
  // tail: t=21 stages last tile (k=736); t=22 drains; t=23 computes
  STEP(0, 2, 736, true, 6);
  STEP(1, 0, 0,   false, 0);
  {
    bf16x8 a[8], b[4];
    LOADFRAGS(2);
    DOMFMA();
  }

  // epilogue: C/D layout col=lane&15, row=(lane>>4)*4+reg  [m89/m91]
  if constexpr (OUT_F32) {
    // f32 direct stores: 16 lanes x 4B contiguous -> full 64B lines
#pragma unroll
    for (int m = 0; m < 8; ++m) {
#pragma unroll
      for (int n = 0; n < 4; ++n) {
        const int row = tM + (wr << 7) + (m << 4) + (l4 << 2);
        const int col = tN + (wc << 6) + (n << 4) + l15;
        const float badd = BIAS ? bias[col] : 0.f;
#pragma unroll
        for (int r = 0; r < 4; ++r)
          ((float*)Cv)[(size_t)(row + r) * E_ + col] = acc[m][n][r] + badd;
      }
    }
  } else {
    // bf16: stage C tile (256x128 u16 = 64KB) in LDS, write back coalesced
    __syncthreads();
    u16* lC = lds;
#pragma unroll
    for (int m = 0; m < 8; ++m)
#pragma unroll
      for (int n = 0; n < 4; ++n) {
        const int row = (wr << 7) + (m << 4) + (l4 << 2);
        const int col = (wc << 6) + (n << 4) + l15;
#pragma unroll
        for (int r = 0; r < 4; ++r)
          lC[(row + r) * BN_ + col] = f2bf(acc[m][n][r]);
      }
    __syncthreads();
#pragma unroll
    for (int p = 0; p < 16; ++p) {
      const int row = (p << 4) + (tid >> 4);     // 16 rows per pass
      const bf16x8 v = *(const bf16x8*)&lC[row * BN_ + (l15 << 3)];
      *(bf16x8*)((u16*)Cv + (size_t)(tM + row) * E_ + tN + (l15 << 3)) = v;
    }
  }
}

// ---------------- per-token attention: 1 wave per token
// att[i,j] = sum_d Q[t,i*96+d]*K[t,j*96+d]; masked softmax over j;
// out2D[b, 512*i + s/8, 96*(s%8)+d] = sum_j p[i,j]*V[t, j*96+d]
__global__ __launch_bounds__(256) void attn_tok(
    const u16* __restrict__ Q, const u16* __restrict__ K,
    const u16* __restrict__ V, const int* __restrict__ mask,
    u16* __restrict__ O)
{
  __shared__ float pl[4][8][8];
  const int tid = threadIdx.x, wave = tid >> 6, lane = tid & 63;
  const int t = blockIdx.x * 4 + wave;
  const int s = t & (S_ - 1);
  const int b = t >> 12;
  const int i = lane >> 3, j = lane & 7;

  const uint4* qp = (const uint4*)(Q + (size_t)t * E_ + i * D_);
  const uint4* kp = (const uint4*)(K + (size_t)t * E_ + j * D_);
  float acc = 0.f;
#pragma unroll
  for (int it = 0; it < 12; ++it) {   // 96 bf16 = 12 x uint4
    const uint4 qv = qp[it], kv = kp[it];
    acc += bflo(qv.x) * bflo(kv.x) + bfhi(qv.x) * bfhi(kv.x);
    acc += bflo(qv.y) * bflo(kv.y) + bfhi(qv.y) * bfhi(kv.y);
    acc += bflo(qv.z) * bflo(kv.z) + bfhi(qv.z) * bfhi(kv.z);
    acc += bflo(qv.w) * bflo(kv.w) + bfhi(qv.w) * bfhi(kv.w);
  }
  // mask==0 -> -1e20 everywhere -> softmax degenerates to 1/8
  float sv = (mask[t] == 0) ? -1e20f : acc;
  sv *= 0.03608439182435161f;          // 1/sqrt(768)
  float mx = sv;
  mx = fmaxf(mx, __shfl_xor(mx, 1));
  mx = fmaxf(mx, __shfl_xor(mx, 2));
  mx = fmaxf(mx, __shfl_xor(mx, 4));
  const float e = __expf(sv - mx);
  float sm = e;
  sm += __shfl_xor(sm, 1);
  sm += __shfl_xor(sm, 2);
  sm += __shfl_xor(sm, 4);
  pl[wave][i][j] = e / sm;
  __syncthreads();

  // PV: lane (i2, db) owns d = db*12 .. db*12+11 of head i2
  const int i2 = lane >> 3, db = lane & 7;
  float o[12] = {};
#pragma unroll
  for (int jj = 0; jj < 8; ++jj) {
    const float pj = pl[wave][i2][jj];
    const uint2* vp = (const uint2*)(V + (size_t)t * E_ + jj * D_ + db * 12);
    const uint2 v0 = vp[0], v1 = vp[1], v2 = vp[2];
    o[0]  += pj * bflo(v0.x);  o[1]  += pj * bfhi(v0.x);
    o[2]  += pj * bflo(v0.y);  o[3]  += pj * bfhi(v0.y);
    o[4]  += pj * bflo(v1.x);  o[5]  += pj * bfhi(v1.x);
    o[6]  += pj * bflo(v1.y);  o[7]  += pj * bfhi(v1.y);
    o[8]  += pj * bflo(v2.x);  o[9]  += pj * bfhi(v2.x);
    o[10] += pj * bflo(v2.y);  o[11] += pj * bfhi(v2.y);
  }
  // scrambled reshape [b,h,s,d] -> [b, 512h + s/8, 96(s%8)+d]
  const size_t row = (size_t)b * S_ + 512 * i2 + (s >> 3);
  u16* op = O + row * E_ + 96 * (s & 7) + db * 12;
  uint2 w0, w1, w2;
  w0.x = pk2(o[0], o[1]);
  w0.y = pk2(o[2], o[3]);
  w1.x = pk2(o[4], o[5]);
  w1.y = pk2(o[6], o[7]);
  w2.x = pk2(o[8], o[9]);
  w2.y = pk2(o[10], o[11]);
  ((uint2*)op)[0] = w0;
  ((uint2*)op)[1] = w1;
  ((uint2*)op)[2] = w2;
}

extern "C" void kernel_launch(void* const* d_in, const int* in_sizes, int n_in,
                              void* d_out, int out_size, void* d_ws, size_t ws_size,
                              hipStream_t stream)
{
  const float* values = (const float*)d_in[0];
  const float* keys   = (const float*)d_in[1];
  const float* query  = (const float*)d_in[2];
  const int*   mask   = (const int*)d_in[3];
  const float* Wv = (const float*)d_in[4];
  const float* Wk = (const float*)d_in[5];
  const float* Wq = (const float*)d_in[6];
  const float* Wo = (const float*)d_in[7];
  const float* bo = (const float*)d_in[8];

  const size_t TE = (size_t)T_ * E_;
  const size_t EE = (size_t)E_ * E_;
  u16* Qb = (u16*)d_ws;          // 25.2 MB each (bf16)
  u16* Kb = Qb + TE;
  u16* Vb = Kb + TE;
  u16* Xq = Vb + TE;             // Xq scratch; later aliased as O2
  u16* Wb = Xq + TE;             // 4 x 1.18 MB bf16 weights (110.1 MB total)
  // Xk/Xv live in d_out (50.33 MB = exactly 2 x TE bf16); dead before the
  // final GEMM overwrites d_out.
  u16* Xk = (u16*)d_out;
  u16* Xv = Xk + TE;

  dim3 blk(256);

  // weights: Wq,Wk,Wv,Wo -> Wb
  conv_w<<<dim3(4 * (E_ * E_ / 4) / 256), blk, 0, stream>>>(Wq, Wk, Wv, Wo, Wb);

  // activations: query->Xq, keys->Xk, values->Xv (one launch)
  conv3<<<dim3(TE / 4 / 256, 3), blk, 0, stream>>>(query, keys, values, Xq, Xk, Xv);

  // batched QKV GEMM: y=0: Xq*Wq->Qb, y=1: Xk*Wk->Kb, y=2: Xv*Wv->Vb
  gemm_nt<true, false, false><<<dim3(T_ / BM_ * NT_, 3), blk, 0, stream>>>(
      Xq, Xk, Xv, Wb, nullptr, Qb, Kb, Vb);

  // attention -> O2 (reuses Xq slot; Xq dead after the batched GEMM)
  attn_tok<<<dim3(T_ / 4), blk, 0, stream>>>(Qb, Kb, Vb, mask, Xq /*O2*/);

  // final GEMM: O2 * Wo^T + bo -> d_out (f32); overwrites Xk/Xv scratch
  gemm_nt<false, true, true><<<dim3(T_ / BM_ * NT_), blk, 0, stream>>>(
      Xq /*O2*/, nullptr, nullptr, Wb + 3 * EE, bo, (float*)d_out, nullptr, nullptr);
}